// Round 14
// baseline (195.754 us; speedup 1.0000x reference)
//
#include <hip/hip_runtime.h>
#include <stdint.h>

typedef _Float16 f16;
typedef _Float16 f16x8 __attribute__((ext_vector_type(8)));
typedef _Float16 f16x4 __attribute__((ext_vector_type(4)));
typedef float f32x4 __attribute__((ext_vector_type(4)));

#define NEGF -1e30f

static __device__ __forceinline__ f32x4 mfma16(f16x8 a, f16x8 b, f32x4 c) {
    return __builtin_amdgcn_mfma_f32_16x16x32_f16(a, b, c, 0, 0, 0);
}

static __device__ __forceinline__ void gload_lds16(const void* g, void* l) {
    __builtin_amdgcn_global_load_lds(
        (const __attribute__((address_space(1))) unsigned int*)g,
        (__attribute__((address_space(3))) unsigned int*)l, 16, 0, 0);
}

// ---------------- elementwise cast f32 -> f16 ----------------
__global__ void cast_f32_f16(const float* __restrict__ src, f16* __restrict__ dst, int n) {
    int idx = blockIdx.x * blockDim.x + threadIdx.x;
    int stride = gridDim.x * blockDim.x;
    for (int i = idx * 4; i < n; i += stride * 4) {
        float4 v = *(const float4*)(src + i);
        f16x4 h;
        h[0] = (f16)v.x; h[1] = (f16)v.y; h[2] = (f16)v.z; h[3] = (f16)v.w;
        *(f16x4*)(dst + i) = h;
    }
}

// ---------------- transpose + cast: dst[c][r] = (f16)src[r][c], src is RxC ----------------
__global__ void transpose_cast(const float* __restrict__ src, f16* __restrict__ dst, int R, int C) {
    __shared__ float tile[32][33];
    const int c0 = blockIdx.x * 32, r0 = blockIdx.y * 32;
    const int tx = threadIdx.x & 31, ty = threadIdx.x >> 5;  // 32 x 8
#pragma unroll
    for (int i = 0; i < 32; i += 8)
        tile[ty + i][tx] = src[(size_t)(r0 + ty + i) * C + c0 + tx];
    __syncthreads();
#pragma unroll
    for (int i = 0; i < 32; i += 8)
        dst[(size_t)(c0 + ty + i) * R + r0 + tx] = (f16)tile[tx][ty + i];
}

// ---------------- QKV GEMM: C = A[M][768] * Bt[2304][768]^T, 2-phase pipelined ----------------
// XCD-chunked swizzle: 576 blocks = 8 XCDs x 72. Each XCD owns 4 contiguous m-rows,
// making the shared B panel (3.5MB) + its A panels L2-resident per XCD.
__global__ void __launch_bounds__(256, 2)
gemm_qkv(const f16* __restrict__ A, const f16* __restrict__ Bt,
         const float* __restrict__ bias,
         f16* __restrict__ Qb, f16* __restrict__ Kb, f16* __restrict__ Vtb, int K) {
    __shared__ alignas(16) f16 As[2][128 * 32];
    __shared__ alignas(16) f16 Bs[2][128 * 32];
    const int t = threadIdx.x;
    const int lane = t & 63, wid = t >> 6;
    const int wm = wid >> 1, wn = wid & 1;
    const int lr = lane & 15, lg = lane >> 4;
    const int flat0 = blockIdx.y * 18 + blockIdx.x;
    const int flat = (flat0 & 7) * 72 + (flat0 >> 3);   // bijective: 576 = 8*72
    const int m0 = (flat / 18) * 128, n0 = (flat % 18) * 128;

    auto stage = [&](int buf, int k0) {
#pragma unroll
        for (int i = 0; i < 2; i++) {
            const int cc = t + i * 256;
            const int rr = cc >> 2, ch = cc & 3;
            gload_lds16(A + (size_t)(m0 + rr) * K + k0 + ch * 8, (f16*)As[buf] + cc * 8);
            gload_lds16(Bt + (size_t)(n0 + rr) * K + k0 + ch * 8, (f16*)Bs[buf] + cc * 8);
        }
    };

    f32x4 acc[4][4] = {};
    stage(0, 0);
    __syncthreads();
    const int NK = K / 32;
    for (int it = 0; it < NK; ++it) {
        const int cur = it & 1;
        if (it + 1 < NK) stage(cur ^ 1, (it + 1) * 32);
        f16x8 af[4], bf[4];
#pragma unroll
        for (int i = 0; i < 4; i++)
            af[i] = *(const f16x8*)((f16*)As[cur] + (wm * 64 + i * 16 + lr) * 32 + lg * 8);
#pragma unroll
        for (int j = 0; j < 4; j++)
            bf[j] = *(const f16x8*)((f16*)Bs[cur] + (wn * 64 + j * 16 + lr) * 32 + lg * 8);
#pragma unroll
        for (int i = 0; i < 4; i++)
#pragma unroll
            for (int j = 0; j < 4; j++)
                acc[i][j] = mfma16(af[i], bf[j], acc[i][j]);
        __syncthreads();
    }
#pragma unroll
    for (int i = 0; i < 4; i++) {
#pragma unroll
        for (int j = 0; j < 4; j++) {
            const int n_g = n0 + wn * 64 + j * 16 + lr;
            const float bv = bias[n_g];
#pragma unroll
            for (int jj = 0; jj < 4; jj++) {
                const int m_g = m0 + wm * 64 + i * 16 + lg * 4 + jj;
                const float val = acc[i][j][jj] + bv;
                if (n_g < 768) {
                    Qb[(((n_g >> 6) * 4096) + m_g) * 64 + (n_g & 63)] = (f16)(val * 0.125f);
                } else if (n_g < 1536) {
                    const int n2 = n_g - 768;
                    Kb[(((n2 >> 6) * 4096) + m_g) * 64 + (n2 & 63)] = (f16)val;
                } else {
                    const int n2 = n_g - 1536;
                    Vtb[((n2 >> 6) * 64 + (n2 & 63)) * 4096 + m_g] = (f16)val;
                }
            }
        }
    }
}

// ---------------- output GEMM: 128x64 tiles, 2-phase pipelined, f32 out ----------------
// XCD-chunked swizzle: 384 blocks = 8 XCDs x 48 (4 m-rows each; B 1.2MB fully L2-resident).
__global__ void __launch_bounds__(256, 3)
gemm_out(const f16* __restrict__ A, const f16* __restrict__ Bt,
         const float* __restrict__ bias, float* __restrict__ Cout, int K, int N) {
    __shared__ alignas(16) f16 As[2][128 * 32];
    __shared__ alignas(16) f16 Bs[2][64 * 32];
    const int t = threadIdx.x;
    const int lane = t & 63, wid = t >> 6;
    const int lr = lane & 15, lg = lane >> 4;
    const int flat0 = blockIdx.y * 12 + blockIdx.x;
    const int flat = (flat0 & 7) * 48 + (flat0 >> 3);   // bijective: 384 = 8*48
    const int m0 = (flat / 12) * 128, n0 = (flat % 12) * 64;

    auto stage = [&](int buf, int k0) {
#pragma unroll
        for (int i = 0; i < 2; i++) {
            const int cc = t + i * 256;
            const int rr = cc >> 2, ch = cc & 3;
            gload_lds16(A + (size_t)(m0 + rr) * K + k0 + ch * 8, (f16*)As[buf] + cc * 8);
        }
        const int rr = t >> 2, ch = t & 3;
        gload_lds16(Bt + (size_t)(n0 + rr) * K + k0 + ch * 8, (f16*)Bs[buf] + t * 8);
    };

    f32x4 acc[2][4] = {};
    stage(0, 0);
    __syncthreads();
    const int NK = K / 32;
    for (int it = 0; it < NK; ++it) {
        const int cur = it & 1;
        if (it + 1 < NK) stage(cur ^ 1, (it + 1) * 32);
        f16x8 af[2], bf[4];
#pragma unroll
        for (int i = 0; i < 2; i++)
            af[i] = *(const f16x8*)((f16*)As[cur] + (wid * 32 + i * 16 + lr) * 32 + lg * 8);
#pragma unroll
        for (int j = 0; j < 4; j++)
            bf[j] = *(const f16x8*)((f16*)Bs[cur] + (j * 16 + lr) * 32 + lg * 8);
#pragma unroll
        for (int i = 0; i < 2; i++)
#pragma unroll
            for (int j = 0; j < 4; j++)
                acc[i][j] = mfma16(af[i], bf[j], acc[i][j]);
        __syncthreads();
    }
#pragma unroll
    for (int i = 0; i < 2; i++) {
#pragma unroll
        for (int j = 0; j < 4; j++) {
            const int n_g = n0 + j * 16 + lr;
            const float bv = bias[n_g];
#pragma unroll
            for (int jj = 0; jj < 4; jj++) {
                const int m_g = m0 + wid * 32 + i * 16 + lg * 4 + jj;
                Cout[(size_t)m_g * N + n_g] = acc[i][j][jj] + bv;
            }
        }
    }
}

// ---------------- flash attention, split-KV, 32 q-rows/wave, 2-phase pipelined ----------------
// Round-13 configuration + EXACTLY ONE change: longest-job-first dispatch. Within each
// head, rr ascends with qb, so the 8-tile (longest) chunks were dispatched LAST on every
// XCD -> ragged tail of maximal blocks. rr' = 143-rr dispatches them first (LPT schedule);
// short 1-2-tile blocks backfill the tail. Pure bijective index remap, zero codegen change.
__global__ void __launch_bounds__(256, 3)
attn_fwd(const f16* __restrict__ Qb, const f16* __restrict__ Kb,
         const f16* __restrict__ Vtb, const float* __restrict__ rel_bias,
         f16* __restrict__ Opart, float* __restrict__ mpart, float* __restrict__ lpart) {
    __shared__ alignas(16) f16 Ks[2][64 * 64];
    __shared__ alignas(16) f16 Vs[2][64 * 64];
    __shared__ alignas(16) f16 Ps[4][32 * 72];
    __shared__ alignas(16) float fac[4][32];
    const int bid0 = blockIdx.x;
    const int bid = (bid0 & 7) * 216 + (bid0 >> 3);   // XCD-chunked swizzle (bijective: 1728=8*216)
    const int h = bid / 144;
    int rr = 143 - (bid % 144);                        // LJF: longest chunks dispatched first
    int qb = 0;
    for (;;) { const int n = (qb + 4) >> 2; if (rr < n) break; rr -= n; ++qb; }
    const int c = rr;
    const int lo = c * 8;
    const int hi = min(lo + 8, 2 * qb + 2);

    const int t = threadIdx.x, lane = t & 63, wid = t >> 6;
    const int lr = lane & 15, lg = lane >> 4;
    const int g = qb * 4 + wid;       // this wave's 32-row group in [0,128)
    const int q0w = g * 32;
    const int ktd = g >> 1;           // diagonal (last valid) tile for this wave
    const f16* Qh = Qb + (size_t)h * 4096 * 64;
    const f16* Kh = Kb + (size_t)h * 4096 * 64;
    const f16* Vh = Vtb + (size_t)h * 64 * 4096;
    const float* rbh = rel_bias + (size_t)h * 4096 * 4096;

    // stage K/V tile: LDS linear dest, pre-swizzled global source (16B chunk XOR row&7)
    auto stage = [&](int buf, int kt) {
        const int kbase = kt * 64;
#pragma unroll
        for (int i = 0; i < 2; i++) {
            const int cc = t + i * 256;
            const int row = cc >> 3;
            const int cswz = (((cc & 7) * 16) ^ ((row & 7) << 4)) >> 1;  // f16 col after swizzle
            gload_lds16(Kh + (size_t)(kbase + row) * 64 + cswz, (f16*)Ks[buf] + cc * 8);
            gload_lds16(Vh + (size_t)row * 4096 + kbase + cswz, (f16*)Vs[buf] + cc * 8);
        }
    };

    // Q fragments (B-operand: col q = q0w + nf*16 + lr, k = kd*32 + lg*8 + j)
    f16x8 qf[2][2];
#pragma unroll
    for (int nf = 0; nf < 2; nf++)
#pragma unroll
        for (int kd = 0; kd < 2; kd++)
            qf[nf][kd] = *(const f16x8*)(Qh + (size_t)(q0w + nf * 16 + lr) * 64 + kd * 32 + lg * 8);

    f32x4 o[2][4] = {};
    float mrow[2] = {NEGF, NEGF};
    float lrow[2] = {0.f, 0.f};

    stage(0, lo);
    __syncthreads();          // prologue drain (once per block)
    for (int kt = lo; kt < hi; kt++) {
        const int kbase = kt * 64;
        const int cur = (kt - lo) & 1;
        if (kt + 1 < hi) stage(cur ^ 1, kt + 1);   // next-tile DMA; drains at END barrier
        if (kt <= ktd) {
            // issue bias loads first; latency hides under QK
            float4 rb[2][4];
#pragma unroll
            for (int nf = 0; nf < 2; nf++)
#pragma unroll
                for (int mf = 0; mf < 4; mf++)
                    rb[nf][mf] = *(const float4*)(rbh + (size_t)(q0w + nf * 16 + lr) * 4096 + kbase + mf * 16 + lg * 4);
            // St[mf][nf]: row k = kbase + mf*16 + lg*4 + jj, col q = q0w + nf*16 + lr
            f32x4 st[4][2] = {};
#pragma unroll
            for (int kd = 0; kd < 2; kd++) {
#pragma unroll
                for (int mf = 0; mf < 4; mf++) {
                    const int r = mf * 16 + lr;
                    const int cf = ((kd * 64 + lg * 16) ^ ((r & 7) << 4)) >> 1;
                    const f16x8 kf = *(const f16x8*)((f16*)Ks[cur] + r * 64 + cf);
#pragma unroll
                    for (int nf = 0; nf < 2; nf++)
                        st[mf][nf] = mfma16(kf, qf[nf][kd], st[mf][nf]);
                }
            }
            const bool diag = (kt == ktd);
            // bias + (diagonal-only) causal + online softmax
#pragma unroll
            for (int nf = 0; nf < 2; nf++) {
                const int q_g = q0w + nf * 16 + lr;
                float mx = NEGF;
#pragma unroll
                for (int mf = 0; mf < 4; mf++) {
                    const float rbv[4] = {rb[nf][mf].x, rb[nf][mf].y, rb[nf][mf].z, rb[nf][mf].w};
#pragma unroll
                    for (int jj = 0; jj < 4; jj++) {
                        float v = st[mf][nf][jj] + rbv[jj];
                        if (diag) {
                            const int k_g = kbase + mf * 16 + lg * 4 + jj;
                            v = (k_g > q_g) ? NEGF : v;
                        }
                        st[mf][nf][jj] = v;
                        mx = fmaxf(mx, v);
                    }
                }
                mx = fmaxf(mx, __shfl_xor(mx, 16));
                mx = fmaxf(mx, __shfl_xor(mx, 32));
                const float mnew = fmaxf(mrow[nf], mx);
                const float fscale = __expf(mrow[nf] - mnew);
                mrow[nf] = mnew;
                float rsum = 0.f;
#pragma unroll
                for (int mf = 0; mf < 4; mf++) {
                    f16x4 pv;
#pragma unroll
                    for (int jj = 0; jj < 4; jj++) {
                        const float p = __expf(st[mf][nf][jj] - mnew);
                        rsum += p;
                        pv[jj] = (f16)p;
                    }
                    *(f16x4*)(&Ps[wid][(nf * 16 + lr) * 72 + mf * 16 + lg * 4]) = pv;
                }
                rsum += __shfl_xor(rsum, 16);
                rsum += __shfl_xor(rsum, 32);
                lrow[nf] = lrow[nf] * fscale + rsum;
                if (lane < 16) fac[wid][nf * 16 + lr] = fscale;
            }
            asm volatile("s_waitcnt lgkmcnt(0)" ::: "memory");
            // rescale O accumulator rows (q = qf2*16 + lg*4 + jj)
#pragma unroll
            for (int qf2 = 0; qf2 < 2; qf2++) {
                const float4 fv = *(const float4*)&fac[wid][qf2 * 16 + lg * 4];
                const float fvv[4] = {fv.x, fv.y, fv.z, fv.w};
#pragma unroll
                for (int df = 0; df < 4; df++)
#pragma unroll
                    for (int jj = 0; jj < 4; jj++)
                        o[qf2][df][jj] *= fvv[jj];
            }
            // O += P @ V  (A = P[q][k] from LDS, Bt = Vt[d][k] from LDS, swizzled)
#pragma unroll
            for (int kk = 0; kk < 2; kk++) {
                f16x8 pa[2], vb[4];
#pragma unroll
                for (int qf2 = 0; qf2 < 2; qf2++)
                    pa[qf2] = *(const f16x8*)(&Ps[wid][(qf2 * 16 + lr) * 72 + kk * 32 + lg * 8]);
#pragma unroll
                for (int df = 0; df < 4; df++) {
                    const int r = df * 16 + lr;
                    const int cf = ((kk * 64 + lg * 16) ^ ((r & 7) << 4)) >> 1;
                    vb[df] = *(const f16x8*)((f16*)Vs[cur] + r * 64 + cf);
                }
#pragma unroll
                for (int qf2 = 0; qf2 < 2; qf2++)
#pragma unroll
                    for (int df = 0; df < 4; df++)
                        o[qf2][df] = mfma16(pa[qf2], vb[df], o[qf2][df]);
            }
        }
        __syncthreads();      // single barrier: drains next-tile DMA
    }

    // write partial (m, l, O[32q][64d] f16) for this (h, g, chunk c)
    const int s = (h * 128 + g) * 8 + c;
    f16* Op = Opart + (size_t)s * 2048;
#pragma unroll
    for (int qf2 = 0; qf2 < 2; qf2++)
#pragma unroll
        for (int df = 0; df < 4; df++)
#pragma unroll
            for (int jj = 0; jj < 4; jj++)
                Op[(qf2 * 16 + lg * 4 + jj) * 64 + df * 16 + lr] = (f16)o[qf2][df][jj];
    if (lg == 0) {
#pragma unroll
        for (int nf = 0; nf < 2; nf++) {
            mpart[(size_t)s * 32 + nf * 16 + lr] = mrow[nf];
            lpart[(size_t)s * 32 + nf * 16 + lr] = lrow[nf];
        }
    }
}

// ---------------- merge partials + normalize -> Ob f16 [4096][768] ----------------
__global__ void __launch_bounds__(256)
merge_norm(const f16* __restrict__ Opart, const float* __restrict__ mpart,
           const float* __restrict__ lpart, f16* __restrict__ Ob) {
    __shared__ float wls[8][32];
    __shared__ float Linv[32];
    const int g = blockIdx.x, h = blockIdx.y;   // g in [0,128)
    const int nc = (g >> 4) + 1;                // chunks containing valid tiles
    const size_t sb = (size_t)(h * 128 + g) * 8;
    const int t = threadIdx.x;
    if (t < 32) {
        float M = NEGF;
#pragma unroll
        for (int i = 0; i < 8; i++)
            if (i < nc) M = fmaxf(M, mpart[(sb + i) * 32 + t]);
        float L = 0.f;
#pragma unroll
        for (int i = 0; i < 8; i++)
            if (i < nc) {
                const float w = __expf(mpart[(sb + i) * 32 + t] - M);
                wls[i][t] = w;
                L += w * lpart[(sb + i) * 32 + t];
            }
        Linv[t] = 1.f / L;
    }
    __syncthreads();
    const int row = t >> 3, dq = t & 7;
    float acc[8] = {};
#pragma unroll
    for (int i = 0; i < 8; i++) {
        if (i < nc) {
            const f16x8 a = *(const f16x8*)(Opart + (sb + i) * 2048 + row * 64 + dq * 8);
            const float w = wls[i][row];
#pragma unroll
            for (int j = 0; j < 8; j++) acc[j] += w * (float)a[j];
        }
    }
    const float inv = Linv[row];
    const int q = g * 32 + row;
    f16x8 ov;
#pragma unroll
    for (int j = 0; j < 8; j++) ov[j] = (f16)(acc[j] * inv);
    *(f16x8*)(Ob + (size_t)q * 768 + h * 64 + dq * 8) = ov;
}

extern "C" void kernel_launch(void* const* d_in, const int* in_sizes, int n_in,
                              void* d_out, int out_size, void* d_ws, size_t ws_size,
                              hipStream_t stream) {
    const float* x = (const float*)d_in[0];
    const float* Wqkv = (const float*)d_in[1];
    const float* bqkv = (const float*)d_in[2];
    const float* Wout = (const float*)d_in[3];
    const float* bout = (const float*)d_in[4];
    const float* rel_bias = (const float*)d_in[5];
    // d_in[6] (causal_mask) synthesized analytically in-kernel
    float* out = (float*)d_out;

    f16* p = (f16*)d_ws;
    f16* xb = p;     p += (size_t)4096 * 768;
    f16* WqkvT = p;  p += (size_t)2304 * 768;
    f16* WoutT = p;  p += (size_t)768 * 768;
    f16* Qb = p;     p += (size_t)12 * 4096 * 64;
    f16* Kb = p;     p += (size_t)12 * 4096 * 64;
    f16* Vtb = p;    p += (size_t)12 * 4096 * 64;
    f16* Ob = p;     p += (size_t)4096 * 768;
    f16* Opart = p;  p += (size_t)12 * 128 * 8 * 2048;  // f16 partials [32q][64d], 50 MB
    float* fp = (float*)p;
    float* mpart = fp;  fp += (size_t)12 * 128 * 8 * 32;
    float* lpart = fp;  fp += (size_t)12 * 128 * 8 * 32;

    cast_f32_f16<<<3072, 256, 0, stream>>>(x, xb, 4096 * 768);
    transpose_cast<<<dim3(2304 / 32, 768 / 32), 256, 0, stream>>>(Wqkv, WqkvT, 768, 2304);
    transpose_cast<<<dim3(768 / 32, 768 / 32), 256, 0, stream>>>(Wout, WoutT, 768, 768);
    gemm_qkv<<<dim3(18, 32), 256, 0, stream>>>(xb, WqkvT, bqkv, Qb, Kb, Vtb, 768);
    attn_fwd<<<dim3(1728), 256, 0, stream>>>(Qb, Kb, Vtb, rel_bias, Opart, mpart, lpart);
    merge_norm<<<dim3(128, 12), 256, 0, stream>>>(Opart, mpart, lpart, Ob);
    gemm_out<<<dim3(12, 32), 256, 0, stream>>>(Ob, WoutT, bout, out, 768, 768);
}

// Round 15
// 194.637 us; speedup vs baseline: 1.0057x; 1.0057x over previous
//
#include <hip/hip_runtime.h>
#include <stdint.h>

typedef _Float16 f16;
typedef _Float16 f16x8 __attribute__((ext_vector_type(8)));
typedef _Float16 f16x4 __attribute__((ext_vector_type(4)));
typedef float f32x4 __attribute__((ext_vector_type(4)));

#define NEGF -1e30f

static __device__ __forceinline__ f32x4 mfma16(f16x8 a, f16x8 b, f32x4 c) {
    return __builtin_amdgcn_mfma_f32_16x16x32_f16(a, b, c, 0, 0, 0);
}

static __device__ __forceinline__ void gload_lds16(const void* g, void* l) {
    __builtin_amdgcn_global_load_lds(
        (const __attribute__((address_space(1))) unsigned int*)g,
        (__attribute__((address_space(3))) unsigned int*)l, 16, 0, 0);
}

// ---------------- elementwise cast f32 -> f16 ----------------
__global__ void cast_f32_f16(const float* __restrict__ src, f16* __restrict__ dst, int n) {
    int idx = blockIdx.x * blockDim.x + threadIdx.x;
    int stride = gridDim.x * blockDim.x;
    for (int i = idx * 4; i < n; i += stride * 4) {
        float4 v = *(const float4*)(src + i);
        f16x4 h;
        h[0] = (f16)v.x; h[1] = (f16)v.y; h[2] = (f16)v.z; h[3] = (f16)v.w;
        *(f16x4*)(dst + i) = h;
    }
}

// ---------------- transpose + cast: dst[c][r] = (f16)src[r][c], src is RxC ----------------
__global__ void transpose_cast(const float* __restrict__ src, f16* __restrict__ dst, int R, int C) {
    __shared__ float tile[32][33];
    const int c0 = blockIdx.x * 32, r0 = blockIdx.y * 32;
    const int tx = threadIdx.x & 31, ty = threadIdx.x >> 5;  // 32 x 8
#pragma unroll
    for (int i = 0; i < 32; i += 8)
        tile[ty + i][tx] = src[(size_t)(r0 + ty + i) * C + c0 + tx];
    __syncthreads();
#pragma unroll
    for (int i = 0; i < 32; i += 8)
        dst[(size_t)(c0 + ty + i) * R + r0 + tx] = (f16)tile[tx][ty + i];
}

// ---------------- QKV GEMM: C = A[M][768] * Bt[2304][768]^T, 2-phase pipelined ----------------
// XCD-chunked swizzle: 576 blocks = 8 XCDs x 72. Each XCD owns 4 contiguous m-rows,
// making the shared B panel (3.5MB) + its A panels L2-resident per XCD.
__global__ void __launch_bounds__(256, 2)
gemm_qkv(const f16* __restrict__ A, const f16* __restrict__ Bt,
         const float* __restrict__ bias,
         f16* __restrict__ Qb, f16* __restrict__ Kb, f16* __restrict__ Vtb, int K) {
    __shared__ alignas(16) f16 As[2][128 * 32];
    __shared__ alignas(16) f16 Bs[2][128 * 32];
    const int t = threadIdx.x;
    const int lane = t & 63, wid = t >> 6;
    const int wm = wid >> 1, wn = wid & 1;
    const int lr = lane & 15, lg = lane >> 4;
    const int flat0 = blockIdx.y * 18 + blockIdx.x;
    const int flat = (flat0 & 7) * 72 + (flat0 >> 3);   // bijective: 576 = 8*72
    const int m0 = (flat / 18) * 128, n0 = (flat % 18) * 128;

    auto stage = [&](int buf, int k0) {
#pragma unroll
        for (int i = 0; i < 2; i++) {
            const int cc = t + i * 256;
            const int rr = cc >> 2, ch = cc & 3;
            gload_lds16(A + (size_t)(m0 + rr) * K + k0 + ch * 8, (f16*)As[buf] + cc * 8);
            gload_lds16(Bt + (size_t)(n0 + rr) * K + k0 + ch * 8, (f16*)Bs[buf] + cc * 8);
        }
    };

    f32x4 acc[4][4] = {};
    stage(0, 0);
    __syncthreads();
    const int NK = K / 32;
    for (int it = 0; it < NK; ++it) {
        const int cur = it & 1;
        if (it + 1 < NK) stage(cur ^ 1, (it + 1) * 32);
        f16x8 af[4], bf[4];
#pragma unroll
        for (int i = 0; i < 4; i++)
            af[i] = *(const f16x8*)((f16*)As[cur] + (wm * 64 + i * 16 + lr) * 32 + lg * 8);
#pragma unroll
        for (int j = 0; j < 4; j++)
            bf[j] = *(const f16x8*)((f16*)Bs[cur] + (wn * 64 + j * 16 + lr) * 32 + lg * 8);
#pragma unroll
        for (int i = 0; i < 4; i++)
#pragma unroll
            for (int j = 0; j < 4; j++)
                acc[i][j] = mfma16(af[i], bf[j], acc[i][j]);
        __syncthreads();
    }
#pragma unroll
    for (int i = 0; i < 4; i++) {
#pragma unroll
        for (int j = 0; j < 4; j++) {
            const int n_g = n0 + wn * 64 + j * 16 + lr;
            const float bv = bias[n_g];
#pragma unroll
            for (int jj = 0; jj < 4; jj++) {
                const int m_g = m0 + wm * 64 + i * 16 + lg * 4 + jj;
                const float val = acc[i][j][jj] + bv;
                if (n_g < 768) {
                    Qb[(((n_g >> 6) * 4096) + m_g) * 64 + (n_g & 63)] = (f16)(val * 0.125f);
                } else if (n_g < 1536) {
                    const int n2 = n_g - 768;
                    Kb[(((n2 >> 6) * 4096) + m_g) * 64 + (n2 & 63)] = (f16)val;
                } else {
                    const int n2 = n_g - 1536;
                    Vtb[((n2 >> 6) * 64 + (n2 & 63)) * 4096 + m_g] = (f16)val;
                }
            }
        }
    }
}

// ---------------- output GEMM: 128x64 tiles, 2-phase pipelined, f32 out ----------------
// XCD-chunked swizzle: 384 blocks = 8 XCDs x 48 (4 m-rows each; B 1.2MB fully L2-resident).
__global__ void __launch_bounds__(256, 3)
gemm_out(const f16* __restrict__ A, const f16* __restrict__ Bt,
         const float* __restrict__ bias, float* __restrict__ Cout, int K, int N) {
    __shared__ alignas(16) f16 As[2][128 * 32];
    __shared__ alignas(16) f16 Bs[2][64 * 32];
    const int t = threadIdx.x;
    const int lane = t & 63, wid = t >> 6;
    const int lr = lane & 15, lg = lane >> 4;
    const int flat0 = blockIdx.y * 12 + blockIdx.x;
    const int flat = (flat0 & 7) * 48 + (flat0 >> 3);   // bijective: 384 = 8*48
    const int m0 = (flat / 12) * 128, n0 = (flat % 12) * 64;

    auto stage = [&](int buf, int k0) {
#pragma unroll
        for (int i = 0; i < 2; i++) {
            const int cc = t + i * 256;
            const int rr = cc >> 2, ch = cc & 3;
            gload_lds16(A + (size_t)(m0 + rr) * K + k0 + ch * 8, (f16*)As[buf] + cc * 8);
        }
        const int rr = t >> 2, ch = t & 3;
        gload_lds16(Bt + (size_t)(n0 + rr) * K + k0 + ch * 8, (f16*)Bs[buf] + t * 8);
    };

    f32x4 acc[2][4] = {};
    stage(0, 0);
    __syncthreads();
    const int NK = K / 32;
    for (int it = 0; it < NK; ++it) {
        const int cur = it & 1;
        if (it + 1 < NK) stage(cur ^ 1, (it + 1) * 32);
        f16x8 af[2], bf[4];
#pragma unroll
        for (int i = 0; i < 2; i++)
            af[i] = *(const f16x8*)((f16*)As[cur] + (wid * 32 + i * 16 + lr) * 32 + lg * 8);
#pragma unroll
        for (int j = 0; j < 4; j++)
            bf[j] = *(const f16x8*)((f16*)Bs[cur] + (j * 16 + lr) * 32 + lg * 8);
#pragma unroll
        for (int i = 0; i < 2; i++)
#pragma unroll
            for (int j = 0; j < 4; j++)
                acc[i][j] = mfma16(af[i], bf[j], acc[i][j]);
        __syncthreads();
    }
#pragma unroll
    for (int i = 0; i < 2; i++) {
#pragma unroll
        for (int j = 0; j < 4; j++) {
            const int n_g = n0 + j * 16 + lr;
            const float bv = bias[n_g];
#pragma unroll
            for (int jj = 0; jj < 4; jj++) {
                const int m_g = m0 + wid * 32 + i * 16 + lg * 4 + jj;
                Cout[(size_t)m_g * N + n_g] = acc[i][j][jj] + bv;
            }
        }
    }
}

// ---------------- flash attention, split-KV, 32 q-rows/wave, 2-phase pipelined ----------------
// ROUND-13 CONFIGURATION (best measured: 194.67us): round-6 structure + XCD-chunked block
// swizzle (1728 = 8*216). LJF dispatch (r14) tested neutral; reverted.
__global__ void __launch_bounds__(256, 3)
attn_fwd(const f16* __restrict__ Qb, const f16* __restrict__ Kb,
         const f16* __restrict__ Vtb, const float* __restrict__ rel_bias,
         f16* __restrict__ Opart, float* __restrict__ mpart, float* __restrict__ lpart) {
    __shared__ alignas(16) f16 Ks[2][64 * 64];
    __shared__ alignas(16) f16 Vs[2][64 * 64];
    __shared__ alignas(16) f16 Ps[4][32 * 72];
    __shared__ alignas(16) float fac[4][32];
    const int bid0 = blockIdx.x;
    const int bid = (bid0 & 7) * 216 + (bid0 >> 3);   // XCD-chunked swizzle (bijective: 1728=8*216)
    const int h = bid / 144;
    int rr = bid % 144;
    int qb = 0;
    for (;;) { const int n = (qb + 4) >> 2; if (rr < n) break; rr -= n; ++qb; }
    const int c = rr;
    const int lo = c * 8;
    const int hi = min(lo + 8, 2 * qb + 2);

    const int t = threadIdx.x, lane = t & 63, wid = t >> 6;
    const int lr = lane & 15, lg = lane >> 4;
    const int g = qb * 4 + wid;       // this wave's 32-row group in [0,128)
    const int q0w = g * 32;
    const int ktd = g >> 1;           // diagonal (last valid) tile for this wave
    const f16* Qh = Qb + (size_t)h * 4096 * 64;
    const f16* Kh = Kb + (size_t)h * 4096 * 64;
    const f16* Vh = Vtb + (size_t)h * 64 * 4096;
    const float* rbh = rel_bias + (size_t)h * 4096 * 4096;

    // stage K/V tile: LDS linear dest, pre-swizzled global source (16B chunk XOR row&7)
    auto stage = [&](int buf, int kt) {
        const int kbase = kt * 64;
#pragma unroll
        for (int i = 0; i < 2; i++) {
            const int cc = t + i * 256;
            const int row = cc >> 3;
            const int cswz = (((cc & 7) * 16) ^ ((row & 7) << 4)) >> 1;  // f16 col after swizzle
            gload_lds16(Kh + (size_t)(kbase + row) * 64 + cswz, (f16*)Ks[buf] + cc * 8);
            gload_lds16(Vh + (size_t)row * 4096 + kbase + cswz, (f16*)Vs[buf] + cc * 8);
        }
    };

    // Q fragments (B-operand: col q = q0w + nf*16 + lr, k = kd*32 + lg*8 + j)
    f16x8 qf[2][2];
#pragma unroll
    for (int nf = 0; nf < 2; nf++)
#pragma unroll
        for (int kd = 0; kd < 2; kd++)
            qf[nf][kd] = *(const f16x8*)(Qh + (size_t)(q0w + nf * 16 + lr) * 64 + kd * 32 + lg * 8);

    f32x4 o[2][4] = {};
    float mrow[2] = {NEGF, NEGF};
    float lrow[2] = {0.f, 0.f};

    stage(0, lo);
    __syncthreads();          // prologue drain (once per block)
    for (int kt = lo; kt < hi; kt++) {
        const int kbase = kt * 64;
        const int cur = (kt - lo) & 1;
        if (kt + 1 < hi) stage(cur ^ 1, kt + 1);   // next-tile DMA; drains at END barrier
        if (kt <= ktd) {
            // issue bias loads first; latency hides under QK
            float4 rb[2][4];
#pragma unroll
            for (int nf = 0; nf < 2; nf++)
#pragma unroll
                for (int mf = 0; mf < 4; mf++)
                    rb[nf][mf] = *(const float4*)(rbh + (size_t)(q0w + nf * 16 + lr) * 4096 + kbase + mf * 16 + lg * 4);
            // St[mf][nf]: row k = kbase + mf*16 + lg*4 + jj, col q = q0w + nf*16 + lr
            f32x4 st[4][2] = {};
#pragma unroll
            for (int kd = 0; kd < 2; kd++) {
#pragma unroll
                for (int mf = 0; mf < 4; mf++) {
                    const int r = mf * 16 + lr;
                    const int cf = ((kd * 64 + lg * 16) ^ ((r & 7) << 4)) >> 1;
                    const f16x8 kf = *(const f16x8*)((f16*)Ks[cur] + r * 64 + cf);
#pragma unroll
                    for (int nf = 0; nf < 2; nf++)
                        st[mf][nf] = mfma16(kf, qf[nf][kd], st[mf][nf]);
                }
            }
            const bool diag = (kt == ktd);
            // bias + (diagonal-only) causal + online softmax
#pragma unroll
            for (int nf = 0; nf < 2; nf++) {
                const int q_g = q0w + nf * 16 + lr;
                float mx = NEGF;
#pragma unroll
                for (int mf = 0; mf < 4; mf++) {
                    const float rbv[4] = {rb[nf][mf].x, rb[nf][mf].y, rb[nf][mf].z, rb[nf][mf].w};
#pragma unroll
                    for (int jj = 0; jj < 4; jj++) {
                        float v = st[mf][nf][jj] + rbv[jj];
                        if (diag) {
                            const int k_g = kbase + mf * 16 + lg * 4 + jj;
                            v = (k_g > q_g) ? NEGF : v;
                        }
                        st[mf][nf][jj] = v;
                        mx = fmaxf(mx, v);
                    }
                }
                mx = fmaxf(mx, __shfl_xor(mx, 16));
                mx = fmaxf(mx, __shfl_xor(mx, 32));
                const float mnew = fmaxf(mrow[nf], mx);
                const float fscale = __expf(mrow[nf] - mnew);
                mrow[nf] = mnew;
                float rsum = 0.f;
#pragma unroll
                for (int mf = 0; mf < 4; mf++) {
                    f16x4 pv;
#pragma unroll
                    for (int jj = 0; jj < 4; jj++) {
                        const float p = __expf(st[mf][nf][jj] - mnew);
                        rsum += p;
                        pv[jj] = (f16)p;
                    }
                    *(f16x4*)(&Ps[wid][(nf * 16 + lr) * 72 + mf * 16 + lg * 4]) = pv;
                }
                rsum += __shfl_xor(rsum, 16);
                rsum += __shfl_xor(rsum, 32);
                lrow[nf] = lrow[nf] * fscale + rsum;
                if (lane < 16) fac[wid][nf * 16 + lr] = fscale;
            }
            asm volatile("s_waitcnt lgkmcnt(0)" ::: "memory");
            // rescale O accumulator rows (q = qf2*16 + lg*4 + jj)
#pragma unroll
            for (int qf2 = 0; qf2 < 2; qf2++) {
                const float4 fv = *(const float4*)&fac[wid][qf2 * 16 + lg * 4];
                const float fvv[4] = {fv.x, fv.y, fv.z, fv.w};
#pragma unroll
                for (int df = 0; df < 4; df++)
#pragma unroll
                    for (int jj = 0; jj < 4; jj++)
                        o[qf2][df][jj] *= fvv[jj];
            }
            // O += P @ V  (A = P[q][k] from LDS, Bt = Vt[d][k] from LDS, swizzled)
#pragma unroll
            for (int kk = 0; kk < 2; kk++) {
                f16x8 pa[2], vb[4];
#pragma unroll
                for (int qf2 = 0; qf2 < 2; qf2++)
                    pa[qf2] = *(const f16x8*)(&Ps[wid][(qf2 * 16 + lr) * 72 + kk * 32 + lg * 8]);
#pragma unroll
                for (int df = 0; df < 4; df++) {
                    const int r = df * 16 + lr;
                    const int cf = ((kk * 64 + lg * 16) ^ ((r & 7) << 4)) >> 1;
                    vb[df] = *(const f16x8*)((f16*)Vs[cur] + r * 64 + cf);
                }
#pragma unroll
                for (int qf2 = 0; qf2 < 2; qf2++)
#pragma unroll
                    for (int df = 0; df < 4; df++)
                        o[qf2][df] = mfma16(pa[qf2], vb[df], o[qf2][df]);
            }
        }
        __syncthreads();      // single barrier: drains next-tile DMA
    }

    // write partial (m, l, O[32q][64d] f16) for this (h, g, chunk c)
    const int s = (h * 128 + g) * 8 + c;
    f16* Op = Opart + (size_t)s * 2048;
#pragma unroll
    for (int qf2 = 0; qf2 < 2; qf2++)
#pragma unroll
        for (int df = 0; df < 4; df++)
#pragma unroll
            for (int jj = 0; jj < 4; jj++)
                Op[(qf2 * 16 + lg * 4 + jj) * 64 + df * 16 + lr] = (f16)o[qf2][df][jj];
    if (lg == 0) {
#pragma unroll
        for (int nf = 0; nf < 2; nf++) {
            mpart[(size_t)s * 32 + nf * 16 + lr] = mrow[nf];
            lpart[(size_t)s * 32 + nf * 16 + lr] = lrow[nf];
        }
    }
}

// ---------------- merge partials + normalize -> Ob f16 [4096][768] ----------------
__global__ void __launch_bounds__(256)
merge_norm(const f16* __restrict__ Opart, const float* __restrict__ mpart,
           const float* __restrict__ lpart, f16* __restrict__ Ob) {
    __shared__ float wls[8][32];
    __shared__ float Linv[32];
    const int g = blockIdx.x, h = blockIdx.y;   // g in [0,128)
    const int nc = (g >> 4) + 1;                // chunks containing valid tiles
    const size_t sb = (size_t)(h * 128 + g) * 8;
    const int t = threadIdx.x;
    if (t < 32) {
        float M = NEGF;
#pragma unroll
        for (int i = 0; i < 8; i++)
            if (i < nc) M = fmaxf(M, mpart[(sb + i) * 32 + t]);
        float L = 0.f;
#pragma unroll
        for (int i = 0; i < 8; i++)
            if (i < nc) {
                const float w = __expf(mpart[(sb + i) * 32 + t] - M);
                wls[i][t] = w;
                L += w * lpart[(sb + i) * 32 + t];
            }
        Linv[t] = 1.f / L;
    }
    __syncthreads();
    const int row = t >> 3, dq = t & 7;
    float acc[8] = {};
#pragma unroll
    for (int i = 0; i < 8; i++) {
        if (i < nc) {
            const f16x8 a = *(const f16x8*)(Opart + (sb + i) * 2048 + row * 64 + dq * 8);
            const float w = wls[i][row];
#pragma unroll
            for (int j = 0; j < 8; j++) acc[j] += w * (float)a[j];
        }
    }
    const float inv = Linv[row];
    const int q = g * 32 + row;
    f16x8 ov;
#pragma unroll
    for (int j = 0; j < 8; j++) ov[j] = (f16)(acc[j] * inv);
    *(f16x8*)(Ob + (size_t)q * 768 + h * 64 + dq * 8) = ov;
}

extern "C" void kernel_launch(void* const* d_in, const int* in_sizes, int n_in,
                              void* d_out, int out_size, void* d_ws, size_t ws_size,
                              hipStream_t stream) {
    const float* x = (const float*)d_in[0];
    const float* Wqkv = (const float*)d_in[1];
    const float* bqkv = (const float*)d_in[2];
    const float* Wout = (const float*)d_in[3];
    const float* bout = (const float*)d_in[4];
    const float* rel_bias = (const float*)d_in[5];
    // d_in[6] (causal_mask) synthesized analytically in-kernel
    float* out = (float*)d_out;

    f16* p = (f16*)d_ws;
    f16* xb = p;     p += (size_t)4096 * 768;
    f16* WqkvT = p;  p += (size_t)2304 * 768;
    f16* WoutT = p;  p += (size_t)768 * 768;
    f16* Qb = p;     p += (size_t)12 * 4096 * 64;
    f16* Kb = p;     p += (size_t)12 * 4096 * 64;
    f16* Vtb = p;    p += (size_t)12 * 4096 * 64;
    f16* Ob = p;     p += (size_t)4096 * 768;
    f16* Opart = p;  p += (size_t)12 * 128 * 8 * 2048;  // f16 partials [32q][64d], 50 MB
    float* fp = (float*)p;
    float* mpart = fp;  fp += (size_t)12 * 128 * 8 * 32;
    float* lpart = fp;  fp += (size_t)12 * 128 * 8 * 32;

    cast_f32_f16<<<3072, 256, 0, stream>>>(x, xb, 4096 * 768);
    transpose_cast<<<dim3(2304 / 32, 768 / 32), 256, 0, stream>>>(Wqkv, WqkvT, 768, 2304);
    transpose_cast<<<dim3(768 / 32, 768 / 32), 256, 0, stream>>>(Wout, WoutT, 768, 768);
    gemm_qkv<<<dim3(18, 32), 256, 0, stream>>>(xb, WqkvT, bqkv, Qb, Kb, Vtb, 768);
    attn_fwd<<<dim3(1728), 256, 0, stream>>>(Qb, Kb, Vtb, rel_bias, Opart, mpart, lpart);
    merge_norm<<<dim3(128, 12), 256, 0, stream>>>(Opart, mpart, lpart, Ob);
    gemm_out<<<dim3(12, 32), 256, 0, stream>>>(Ob, WoutT, bout, out, 768, 768);
}